// Round 4
// baseline (802.296 us; speedup 1.0000x reference)
//
#include <hip/hip_runtime.h>

#define NEG_SLOPE 0.2f
#define LN_EPS 1e-5f
#define NEGINF -3.0e38f

typedef float f2 __attribute__((ext_vector_type(2)));

__device__ __forceinline__ f2 sp2(float x){ return (f2){x, x}; }
__device__ __forceinline__ f2 fma2(f2 a, f2 b, f2 c){
#if __has_builtin(__builtin_elementwise_fma)
  return __builtin_elementwise_fma(a, b, c);
#else
  f2 r; r.x = fmaf(a.x, b.x, c.x); r.y = fmaf(a.y, b.y, c.y); return r;
#endif
}
__device__ __forceinline__ f2 max2(f2 a, f2 b){
#if __has_builtin(__builtin_elementwise_max)
  return __builtin_elementwise_max(a, b);
#else
  f2 r; r.x = fmaxf(a.x, b.x); r.y = fmaxf(a.y, b.y); return r;
#endif
}
__device__ __forceinline__ f2 min2(f2 a, f2 b){
#if __has_builtin(__builtin_elementwise_min)
  return __builtin_elementwise_min(a, b);
#else
  f2 r; r.x = fminf(a.x, b.x); r.y = fminf(a.y, b.y); return r;
#endif
}

__device__ __forceinline__ float wsum64(float v){
  #pragma unroll
  for (int o = 32; o >= 1; o >>= 1) v += __shfl_xor(v, o);
  return v;
}
__device__ __forceinline__ float wmax64(float v){
  #pragma unroll
  for (int o = 32; o >= 1; o >>= 1) v = fmaxf(v, __shfl_xor(v, o));
  return v;
}
// sum within each 32-lane half (shfl -> ds pipe, off-VALU)
__device__ __forceinline__ float gsum32(float v){
  #pragma unroll
  for (int o = 16; o >= 1; o >>= 1) v += __shfl_xor(v, o);
  return v;
}
__device__ __forceinline__ float rlF(float v, int lane){
  return __int_as_float(__builtin_amdgcn_readlane(__float_as_int(v), lane));
}
__device__ __forceinline__ int rlI(int v, int lane){
  return __builtin_amdgcn_readlane(v, lane);
}

// ---------------- CSR build ----------------
__global__ void k_count(const int* __restrict__ dst, int* __restrict__ deg, int E){
  int e = blockIdx.x * blockDim.x + threadIdx.x;
  if (e < E) atomicAdd(&deg[dst[e]], 1);
}

__global__ void k_scan_blk(const int* __restrict__ deg, int* __restrict__ part,
                           int* __restrict__ sums, int n){
  __shared__ int buf[256];
  int t = threadIdx.x, i = blockIdx.x * 256 + t;
  int v = (i < n) ? deg[i] : 0;
  buf[t] = v; __syncthreads();
  #pragma unroll
  for (int off = 1; off < 256; off <<= 1){
    int x = (t >= off) ? buf[t - off] : 0;
    __syncthreads(); buf[t] += x; __syncthreads();
  }
  if (i < n) part[i] = buf[t] - v;
  if (t == 255) sums[blockIdx.x] = buf[255];
}

__global__ void k_scan_top(int* __restrict__ sums, int nb){
  __shared__ int buf[256];
  int t = threadIdx.x;
  int v = (t < nb) ? sums[t] : 0;
  buf[t] = v; __syncthreads();
  #pragma unroll
  for (int off = 1; off < 256; off <<= 1){
    int x = (t >= off) ? buf[t - off] : 0;
    __syncthreads(); buf[t] += x; __syncthreads();
  }
  if (t < nb) sums[t] = buf[t] - v;
}

__global__ void k_scan_add(int* __restrict__ ptr, const int* __restrict__ sums,
                           int n, int Etot){
  int i = blockIdx.x * 256 + threadIdx.x;
  if (i < n) ptr[i] += sums[blockIdx.x];
  if (i == 0) ptr[n] = Etot;
}

__global__ void k_fill(const int* __restrict__ dst, const int* __restrict__ src,
                       int* __restrict__ cnt, const int* __restrict__ ptr,
                       int* __restrict__ eid, int* __restrict__ csrc,
                       int* __restrict__ cdst, int E){
  int e = blockIdx.x * blockDim.x + threadIdx.x;
  if (e < E){
    int d = dst[e];
    int pos = atomicAdd(&cnt[d], 1);
    int p = ptr[d] + pos;
    eid[p] = e;
    csrc[p] = src[e];
    cdst[p] = d;
  }
}

// loop_attr: wave per node, 4 edge-slots x 16 dims
__launch_bounds__(256)
__global__ void k_loop_attr(const float* __restrict__ eattr, const int* __restrict__ ptr,
                            const int* __restrict__ eid, float* __restrict__ lattr, int N){
  int node = blockIdx.x * 4 + (threadIdx.x >> 6);
  if (node >= N) return;
  int t = threadIdx.x & 63;
  int dim = t & 15, slot = t >> 4;
  int beg = ptr[node], end = ptr[node + 1];
  float s = 0.f;
  for (int i = beg + slot; i < end; i += 4){
    int e = eid[i];
    s += eattr[(size_t)e * 16 + dim];
  }
  s += __shfl_xor(s, 16);
  s += __shfl_xor(s, 32);
  if (slot == 0){
    float dg = (float)(end - beg);
    lattr[node * 16 + dim] = s / fmaxf(dg, 1.0f);
  }
}

// ---------------- Y[M,128] = X[M,128] @ W[128,128] + b (packed fp32) ----------------
__launch_bounds__(256)
__global__ void k_gemm128(const float* __restrict__ X, const float* __restrict__ W,
                          const float* __restrict__ bias, float* __restrict__ Y, int M){
  __shared__ float Xs[64][129];
  int t = threadIdx.x;
  int rowBase = blockIdx.x * 64;
  int lr = t >> 5, lc = (t & 31) * 4;
  #pragma unroll
  for (int p = 0; p < 8; p++){
    int r = p * 8 + lr, gr = rowBase + r;
    float4 v = make_float4(0.f, 0.f, 0.f, 0.f);
    if (gr < M) v = *(const float4*)(X + (size_t)gr * 128 + lc);
    Xs[r][lc] = v.x; Xs[r][lc + 1] = v.y; Xs[r][lc + 2] = v.z; Xs[r][lc + 3] = v.w;
  }
  __syncthreads();
  int c0 = (t & 31) * 4, r0 = (t >> 5) * 8;
  float4 bv = *(const float4*)(bias + c0);
  f2 acc[8][2];
  #pragma unroll
  for (int i = 0; i < 8; i++){ acc[i][0] = (f2){bv.x, bv.y}; acc[i][1] = (f2){bv.z, bv.w}; }
  for (int k = 0; k < 128; k++){
    float4 wv = *(const float4*)(W + k * 128 + c0);
    f2 w0 = (f2){wv.x, wv.y}, w1 = (f2){wv.z, wv.w};
    #pragma unroll
    for (int i = 0; i < 8; i++){
      f2 xx = sp2(Xs[r0 + i][k]);
      acc[i][0] = fma2(xx, w0, acc[i][0]);
      acc[i][1] = fma2(xx, w1, acc[i][1]);
    }
  }
  #pragma unroll
  for (int i = 0; i < 8; i++){
    int gr = rowBase + r0 + i;
    if (gr < M){
      float4 o; o.x = acc[i][0].x; o.y = acc[i][0].y; o.z = acc[i][1].x; o.w = acc[i][1].y;
      *(float4*)(Y + (size_t)gr * 128 + c0) = o;
    }
  }
}

__launch_bounds__(256)
__global__ void k_gemm_lr(const float* __restrict__ X,
                          const float* __restrict__ WL, const float* __restrict__ bL,
                          const float* __restrict__ WR, const float* __restrict__ bR,
                          float* __restrict__ YL, float* __restrict__ YR, int M){
  __shared__ float Xs[64][129];
  int t = threadIdx.x;
  int rowBase = blockIdx.x * 64;
  int lr = t >> 5, lc = (t & 31) * 4;
  #pragma unroll
  for (int p = 0; p < 8; p++){
    int r = p * 8 + lr, gr = rowBase + r;
    float4 v = make_float4(0.f, 0.f, 0.f, 0.f);
    if (gr < M) v = *(const float4*)(X + (size_t)gr * 128 + lc);
    Xs[r][lc] = v.x; Xs[r][lc + 1] = v.y; Xs[r][lc + 2] = v.z; Xs[r][lc + 3] = v.w;
  }
  __syncthreads();
  int c0 = (t & 31) * 4, r0 = (t >> 5) * 8;
  float4 bv = *(const float4*)(bL + c0);
  float4 cv = *(const float4*)(bR + c0);
  f2 aL[8][2], aR[8][2];
  #pragma unroll
  for (int i = 0; i < 8; i++){
    aL[i][0] = (f2){bv.x, bv.y}; aL[i][1] = (f2){bv.z, bv.w};
    aR[i][0] = (f2){cv.x, cv.y}; aR[i][1] = (f2){cv.z, cv.w};
  }
  for (int k = 0; k < 128; k++){
    float4 wl = *(const float4*)(WL + k * 128 + c0);
    float4 wr = *(const float4*)(WR + k * 128 + c0);
    f2 l0 = (f2){wl.x, wl.y}, l1 = (f2){wl.z, wl.w};
    f2 r0v = (f2){wr.x, wr.y}, r1v = (f2){wr.z, wr.w};
    #pragma unroll
    for (int i = 0; i < 8; i++){
      f2 xx = sp2(Xs[r0 + i][k]);
      aL[i][0] = fma2(xx, l0, aL[i][0]); aL[i][1] = fma2(xx, l1, aL[i][1]);
      aR[i][0] = fma2(xx, r0v, aR[i][0]); aR[i][1] = fma2(xx, r1v, aR[i][1]);
    }
  }
  #pragma unroll
  for (int i = 0; i < 8; i++){
    int gr = rowBase + r0 + i;
    if (gr < M){
      float4 o; o.x = aL[i][0].x; o.y = aL[i][0].y; o.z = aL[i][1].x; o.w = aL[i][1].y;
      *(float4*)(YL + (size_t)gr * 128 + c0) = o;
      float4 q; q.x = aR[i][0].x; q.y = aR[i][0].y; q.z = aR[i][1].x; q.w = aR[i][1].y;
      *(float4*)(YR + (size_t)gr * 128 + c0) = q;
    }
  }
}

// ---------------- Phase P: edge-parallel logits ----------------
// Items p in [0, M=E+N): p<E real CSR edge (csrc/cdst/eid), p>=E self loop of node p-E
// (ea = lattr row, src=dst=node). Wave owns 64 consecutive items -> perfectly balanced.
// Writes logit4[p][h], h=0..3.
__launch_bounds__(256)
__global__ void k_logits(const float* __restrict__ xl, const float* __restrict__ xr,
                         const float* __restrict__ eattr, const float* __restrict__ lattr,
                         const int* __restrict__ csrc, const int* __restrict__ cdst,
                         const int* __restrict__ eid,
                         const float* __restrict__ We, const float* __restrict__ att,
                         float* __restrict__ logit4, int E, int M){
  const int t = threadIdx.x & 63;
  const int base = (blockIdx.x * 4 + (threadIdx.x >> 6)) * 64;
  if (base >= M) return;
  const int cnt = min(64, M - base);

  f2 we[16];
  #pragma unroll
  for (int k = 0; k < 16; k++) we[k] = (f2){We[k * 128 + t], We[k * 128 + 64 + t]};
  const f2 attv = (f2){att[t], att[64 + t]};

  // lane-parallel preload of (src, dst, edge-row) triples
  int sl = 0, dl = 0, el = -1;
  {
    int idx = base + t;
    if (idx < M){
      if (idx < E){ sl = csrc[idx]; dl = cdst[idx]; el = eid[idx]; }
      else        { sl = idx - E;   dl = idx - E;   el = -1; }
    }
  }

  // prefetch item 0
  int s = rlI(sl, 0), d = rlI(dl, 0), e = rlI(el, 0);
  const float* eb = (e >= 0) ? (eattr + (size_t)e * 16) : (lattr + (size_t)s * 16);
  const float *xp = xl + (size_t)s * 128, *rp = xr + (size_t)d * 128;
  f2 X = (f2){xp[t], xp[64 + t]};
  f2 R = (f2){rp[t], rp[64 + t]};
  const float4* ep = (const float4*)eb;
  float4 A0 = ep[0], A1 = ep[1], A2 = ep[2], A3 = ep[3];

  for (int i = 0; i < cnt; i++){
    f2 Xc = X, Rc = R;
    float4 B0 = A0, B1 = A1, B2 = A2, B3 = A3;
    if (i + 1 < cnt){
      s = rlI(sl, i + 1); d = rlI(dl, i + 1); e = rlI(el, i + 1);
      const float* eb2 = (e >= 0) ? (eattr + (size_t)e * 16) : (lattr + (size_t)s * 16);
      const float *x2 = xl + (size_t)s * 128, *r2 = xr + (size_t)d * 128;
      X = (f2){x2[t], x2[64 + t]};
      R = (f2){r2[t], r2[64 + t]};
      const float4* ep2 = (const float4*)eb2;
      A0 = ep2[0]; A1 = ep2[1]; A2 = ep2[2]; A3 = ep2[3];
    }
    f2 ee = sp2(B0.x) * we[0];
    ee = fma2(sp2(B0.y), we[1],  ee); ee = fma2(sp2(B0.z), we[2],  ee); ee = fma2(sp2(B0.w), we[3],  ee);
    ee = fma2(sp2(B1.x), we[4],  ee); ee = fma2(sp2(B1.y), we[5],  ee); ee = fma2(sp2(B1.z), we[6],  ee);
    ee = fma2(sp2(B1.w), we[7],  ee); ee = fma2(sp2(B2.x), we[8],  ee); ee = fma2(sp2(B2.y), we[9],  ee);
    ee = fma2(sp2(B2.z), we[10], ee); ee = fma2(sp2(B2.w), we[11], ee); ee = fma2(sp2(B3.x), we[12], ee);
    ee = fma2(sp2(B3.y), we[13], ee); ee = fma2(sp2(B3.z), we[14], ee); ee = fma2(sp2(B3.w), we[15], ee);
    f2 m = Xc + Rc + ee;
    m = fma2(sp2(NEG_SLOPE), min2(m, sp2(0.f)), max2(m, sp2(0.f)));  // LeakyReLU
    f2 pr = m * attv;
    float l0 = gsum32(pr.x);   // lanes 0-31: h0 ; 32-63: h1
    float l1 = gsum32(pr.y);   // lanes 0-31: h2 ; 32-63: h3
    if ((t & 31) == 0){
      size_t p4 = (size_t)(base + i) * 4 + (t >> 5);
      logit4[p4] = l0;
      logit4[p4 + 2] = l1;
    }
  }
}

// ---------------- Phase S: node-parallel softmax + aggregation ----------------
__launch_bounds__(256)
__global__ void k_agg(const float* __restrict__ xl,
                      const int* __restrict__ csrc, const int* __restrict__ ptr,
                      const float* __restrict__ logit4,
                      const float* __restrict__ cb, float* __restrict__ hout,
                      int N, int E){
  const int t = threadIdx.x & 63;
  const int n = blockIdx.x * 4 + (threadIdx.x >> 6);
  if (n >= N) return;
  const bool lo = (t < 32);
  const int beg = __builtin_amdgcn_readfirstlane(ptr[n]);
  const int end = __builtin_amdgcn_readfirstlane(ptr[n + 1]);
  const int deg = end - beg;
  const float4* LG = (const float4*)logit4;

  // per-lane strided max (lane t owns CSR pos beg+t, beg+64+t, ...)
  float4 pm = make_float4(NEGINF, NEGINF, NEGINF, NEGINF);
  float4 L0 = pm; int sv0 = 0;
  const bool have0 = (t < deg);
  if (have0){
    L0 = LG[(size_t)beg + t];
    sv0 = csrc[beg + t];
    pm = L0;
  }
  for (int b = 64; b < deg; b += 64){
    if (t + b < deg){
      float4 L = LG[(size_t)beg + b + t];
      pm.x = fmaxf(pm.x, L.x); pm.y = fmaxf(pm.y, L.y);
      pm.z = fmaxf(pm.z, L.z); pm.w = fmaxf(pm.w, L.w);
    }
  }
  float4 sf = LG[(size_t)E + n];   // self-loop logits (uniform broadcast)
  float mx0 = fmaxf(wmax64(pm.x), sf.x);
  float mx1 = fmaxf(wmax64(pm.y), sf.y);
  float mx2 = fmaxf(wmax64(pm.z), sf.z);
  float mx3 = fmaxf(wmax64(pm.w), sf.w);

  // denominators (cache chunk-0 exps)
  float4 e4 = make_float4(0.f, 0.f, 0.f, 0.f);
  if (have0){
    e4.x = __expf(L0.x - mx0); e4.y = __expf(L0.y - mx1);
    e4.z = __expf(L0.z - mx2); e4.w = __expf(L0.w - mx3);
  }
  float4 pd = e4;
  for (int b = 64; b < deg; b += 64){
    if (t + b < deg){
      float4 L = LG[(size_t)beg + b + t];
      pd.x += __expf(L.x - mx0); pd.y += __expf(L.y - mx1);
      pd.z += __expf(L.z - mx2); pd.w += __expf(L.w - mx3);
    }
  }
  float es0 = __expf(sf.x - mx0), es1 = __expf(sf.y - mx1);
  float es2 = __expf(sf.z - mx2), es3 = __expf(sf.w - mx3);
  float rden0 = 1.f / (wsum64(pd.x) + es0);
  float rden1 = 1.f / (wsum64(pd.y) + es1);
  float rden2 = 1.f / (wsum64(pd.z) + es2);
  float rden3 = 1.f / (wsum64(pd.w) + es3);

  // self contribution
  f2 xs = (f2){xl[(size_t)n * 128 + t], xl[(size_t)n * 128 + 64 + t]};
  f2 aself = (f2){ lo ? es0 * rden0 : es1 * rden1,
                   lo ? es2 * rden2 : es3 * rden3 };
  f2 acc = aself * xs;

  // aggregation over edges, chunked, dist-2 prefetch of xl gathers
  for (int b = 0; b < deg; b += 64){
    int cnt = min(64, deg - b);
    int sv; float4 a4;
    if (b == 0){
      sv = sv0;
      a4.x = e4.x * rden0; a4.y = e4.y * rden1;
      a4.z = e4.z * rden2; a4.w = e4.w * rden3;
    } else {
      sv = 0; a4 = make_float4(0.f, 0.f, 0.f, 0.f);
      if (t < cnt){
        sv = csrc[beg + b + t];
        float4 L = LG[(size_t)beg + b + t];
        a4.x = __expf(L.x - mx0) * rden0; a4.y = __expf(L.y - mx1) * rden1;
        a4.z = __expf(L.z - mx2) * rden2; a4.w = __expf(L.w - mx3) * rden3;
      }
    }
    int sA = rlI(sv, 0);
    f2 g0 = (f2){xl[(size_t)sA * 128 + t], xl[(size_t)sA * 128 + 64 + t]};
    f2 g1 = sp2(0.f);
    if (cnt > 1){
      int sB = rlI(sv, 1);
      g1 = (f2){xl[(size_t)sB * 128 + t], xl[(size_t)sB * 128 + 64 + t]};
    }
    for (int i = 0; i < cnt; i++){
      f2 g = (i & 1) ? g1 : g0;
      if (i + 2 < cnt){
        int sN = rlI(sv, i + 2);
        f2 gn = (f2){xl[(size_t)sN * 128 + t], xl[(size_t)sN * 128 + 64 + t]};
        if (i & 1) g1 = gn; else g0 = gn;
      }
      float a0 = rlF(a4.x, i), a1 = rlF(a4.y, i), a2 = rlF(a4.z, i), a3 = rlF(a4.w, i);
      f2 aa = (f2){ lo ? a0 : a1, lo ? a2 : a3 };
      acc = fma2(aa, g, acc);
    }
  }

  f2 o = acc + (f2){cb[t], cb[64 + t]};
  float o0 = o.x > 0.f ? o.x : expm1f(o.x);
  float o1 = o.y > 0.f ? o.y : expm1f(o.y);
  hout[(size_t)n * 128 + t] = o0;
  hout[(size_t)n * 128 + 64 + t] = o1;
}

// ---------------- LayerNorm + ReLU-MLP head ----------------
__launch_bounds__(256)
__global__ void k_head(const float* __restrict__ h, const float* __restrict__ g,
                       const float* __restrict__ b, const float* __restrict__ w1,
                       const float* __restrict__ b1, const float* __restrict__ w2,
                       const float* __restrict__ b2, float* __restrict__ out, int N){
  __shared__ float sn[4][128];
  const int t = threadIdx.x & 63, wv = threadIdx.x >> 6;
  const int node = blockIdx.x * 4 + wv;
  float h0 = 0.f, h1 = 0.f;
  if (node < N){ h0 = h[(size_t)node * 128 + t]; h1 = h[(size_t)node * 128 + 64 + t]; }
  float mu = wsum64(h0 + h1) * (1.f / 128.f);
  float d0 = h0 - mu, d1 = h1 - mu;
  float var = wsum64(d0 * d0 + d1 * d1) * (1.f / 128.f);
  float rstd = rsqrtf(var + LN_EPS);
  sn[wv][t]      = d0 * rstd * g[t]      + b[t];
  sn[wv][t + 64] = d1 * rstd * g[t + 64] + b[t + 64];
  __syncthreads();
  float a = b1[t];
  #pragma unroll
  for (int k4 = 0; k4 < 32; k4++){
    float4 v = *(const float4*)&sn[wv][k4 * 4];
    a = fmaf(v.x, w1[(k4 * 4 + 0) * 64 + t], a);
    a = fmaf(v.y, w1[(k4 * 4 + 1) * 64 + t], a);
    a = fmaf(v.z, w1[(k4 * 4 + 2) * 64 + t], a);
    a = fmaf(v.w, w1[(k4 * 4 + 3) * 64 + t], a);
  }
  a = fmaxf(a, 0.f);
  float p0 = a * w2[t * 3 + 0], p1 = a * w2[t * 3 + 1], p2 = a * w2[t * 3 + 2];
  p0 = wsum64(p0); p1 = wsum64(p1); p2 = wsum64(p2);
  if (node < N && t == 0){
    out[(size_t)node * 3 + 0] = p0 + b2[0];
    out[(size_t)node * 3 + 1] = p1 + b2[1];
    out[(size_t)node * 3 + 2] = p2 + b2[2];
  }
}

extern "C" void kernel_launch(void* const* d_in, const int* in_sizes, int n_in,
                              void* d_out, int out_size, void* d_ws, size_t ws_size,
                              hipStream_t stream){
  const float* x    = (const float*)d_in[0];
  const int*   ei   = (const int*)d_in[1];
  const float* ea   = (const float*)d_in[2];
  const float* in_w = (const float*)d_in[3];
  const float* in_b = (const float*)d_in[4];
  const float* Wl   = (const float*)d_in[5];
  const float* bl   = (const float*)d_in[6];
  const float* Wr   = (const float*)d_in[7];
  const float* br   = (const float*)d_in[8];
  const float* We   = (const float*)d_in[9];
  const float* att  = (const float*)d_in[10];
  const float* cb   = (const float*)d_in[11];
  const float* lng  = (const float*)d_in[12];
  const float* lnb  = (const float*)d_in[13];
  const float* h1w  = (const float*)d_in[14];
  const float* h1b  = (const float*)d_in[15];
  const float* h2w  = (const float*)d_in[16];
  const float* h2b  = (const float*)d_in[17];
  float* out = (float*)d_out;

  int N = in_sizes[0] / 128;
  int E = in_sizes[1] / 2;
  int M = E + N;
  const int* src = ei;
  const int* dst = ei + E;

  char* w = (char*)d_ws;
  size_t off = 0;
  auto alloc = [&](size_t bytes) -> char* {
    char* p = w + off;
    off = (off + bytes + 255) & ~(size_t)255;
    return p;
  };
  int*   deg   = (int*)alloc((size_t)N * 4);
  int*   cnt   = (int*)alloc((size_t)N * 4);
  int*   ptr   = (int*)alloc((size_t)(N + 1) * 4);
  int*   eid   = (int*)alloc((size_t)E * 4);
  int*   csrc  = (int*)alloc((size_t)E * 4);
  int*   cdst  = (int*)alloc((size_t)E * 4);
  int*   bsum  = (int*)alloc(256 * 4);
  float* lattr = (float*)alloc((size_t)N * 16 * 4);
  float* lg4   = (float*)alloc((size_t)M * 4 * 4);
  float* h     = (float*)alloc((size_t)N * 128 * 4);
  float* xlb   = (float*)alloc((size_t)N * 128 * 4);
  float* xrb   = (float*)alloc((size_t)N * 128 * 4);

  int nb = (N + 255) / 256;
  hipMemsetAsync(deg, 0, (size_t)N * 4, stream);
  hipMemsetAsync(cnt, 0, (size_t)N * 4, stream);
  k_count<<<(E + 255) / 256, 256, 0, stream>>>(dst, deg, E);
  k_scan_blk<<<nb, 256, 0, stream>>>(deg, ptr, bsum, N);
  k_scan_top<<<1, 256, 0, stream>>>(bsum, nb);
  k_scan_add<<<nb, 256, 0, stream>>>(ptr, bsum, N, E);
  k_fill<<<(E + 255) / 256, 256, 0, stream>>>(dst, src, cnt, ptr, eid, csrc, cdst, E);
  k_loop_attr<<<(N + 3) / 4, 256, 0, stream>>>(ea, ptr, eid, lattr, N);

  k_gemm128<<<(N + 63) / 64, 256, 0, stream>>>(x, in_w, in_b, h, N);
  int pblocks = ((M + 63) / 64 + 3) / 4;
  for (int l = 0; l < 2; l++){
    k_gemm_lr<<<(N + 63) / 64, 256, 0, stream>>>(h, Wl + l * 16384, bl + l * 128,
                                                 Wr + l * 16384, br + l * 128, xlb, xrb, N);
    k_logits<<<pblocks, 256, 0, stream>>>(xlb, xrb, ea, lattr, csrc, cdst, eid,
                                          We + l * 2048, att + l * 128, lg4, E, M);
    k_agg<<<(N + 3) / 4, 256, 0, stream>>>(xlb, csrc, ptr, lg4, cb + l * 128, h, N, E);
  }
  k_head<<<(N + 3) / 4, 256, 0, stream>>>(h, lng, lnb, h1w, h1b, h2w, h2b, out, N);
}